// Round 6
// baseline (1921.507 us; speedup 1.0000x reference)
//
#include <hip/hip_runtime.h>
#include <math.h>

typedef unsigned int uint32;
typedef unsigned short ushort_t;

typedef __attribute__((ext_vector_type(8))) short short8;
typedef __attribute__((ext_vector_type(4))) float floatx4;

#define SEQL 2048
#define DIMC 768
#define NHEAD 12
#define HDIM 64
#define HIDV 2042
#define HIDP 2048
#define NVOCAB 32000
#define QKS 1536             // fused Q|K row stride
#define QSZ (DIMC*DIMC)      // 589824
#define PSZ (HIDP*DIMC)      // 1572864
#define W2SRC (DIMC*HIDV)    // 1568256
#define LSTR (4*QSZ + 3*PSZ) // per-layer converted-weight stride (elements) = 7077888

__device__ __forceinline__ ushort_t f2bf(float f) {
    uint32 u = __float_as_uint(f);
    u += 0x7FFFu + ((u >> 16) & 1u);   // round-to-nearest-even
    return (ushort_t)(u >> 16);
}
__device__ __forceinline__ float bf2f(ushort_t h) {
    return __uint_as_float(((uint32)h) << 16);
}

union Frag { short8 s8; uint32 u[4]; ushort_t us[8]; };

// async global->LDS 16B copy (dest must be linear in lane order within wave)
#define GLOAD_LDS16(g, l) \
    __builtin_amdgcn_global_load_lds((const __attribute__((address_space(1))) void*)(g), \
                                     (__attribute__((address_space(3))) void*)(l), 16, 0, 0)

// ---------------- LDS-staged GEMM, double-buffered 2-phase, XCD-swizzled ---
// C[M,N] (=|+=) A[M,K] * B[N,K]^T, bf16 in. BM,BN in {64,128}; 4 waves (2x2),
// wave tile (BM/2)x(BN/2). stage(t+1) issues before compute(t); single
// __syncthreads per iter drains vmcnt (prefetch flight overlaps MFMA).
// Block swizzle: bijective XCD chunking (requires gridDim.x*gridDim.y % 8 == 0).
// OUTMODE: 0 = f32 store, 1 = bf16 store, 2 = += f32 (residual),
//          4 = silu-pair: B is interleaved W13 (even 16-group = w1, odd = w3);
//              writes silu(y1)*y3 bf16 to C with ld = ldc, cols halved.
template<int BM, int BN, int OUTMODE>
__global__ __launch_bounds__(256)
void gemm_lds_kernel(const ushort_t* __restrict__ A, int lda,
                     const ushort_t* __restrict__ B, int ldb,
                     void* __restrict__ C, int ldc, int K)
{
    constexpr int WTM = BM / 32;
    constexpr int WTN = BN / 32;
    __shared__ __align__(16) ushort_t As[2][BM * 32];
    __shared__ __align__(16) ushort_t Bs[2][BN * 32];

    const int tid = threadIdx.x;
    // bijective XCD swizzle: lid = xcd*(nwg/8) + pos
    const int nwg  = gridDim.x * gridDim.y;
    const int lid0 = blockIdx.y * gridDim.x + blockIdx.x;
    const int lid  = (lid0 & 7) * (nwg >> 3) + (lid0 >> 3);
    const int bx = lid % gridDim.x;
    const int by = lid / gridDim.x;

    const int wid = tid >> 6, lane = tid & 63;
    const int wm = wid & 1, wn = wid >> 1;
    const int r = lane & 15, quad = lane >> 4;
    const int m0 = bx * BM;
    const int n0 = by * BN;

    floatx4 acc[WTM][WTN];
#pragma unroll
    for (int i = 0; i < WTM; ++i)
#pragma unroll
        for (int j = 0; j < WTN; ++j) acc[i][j] = (floatx4){0.f, 0.f, 0.f, 0.f};

    const int row_a = tid >> 2;          // 0..63
    const int col8  = (tid & 3) * 8;
    const ushort_t* gA = A + (size_t)(m0 + row_a) * lda + col8;
    const ushort_t* gB = B + (size_t)(n0 + row_a) * ldb + col8;

    auto stage = [&](int buf, int k0) {
        GLOAD_LDS16(gA + k0, &As[buf][(size_t)tid * 8]);
        if (BM == 128) GLOAD_LDS16(gA + (size_t)64 * lda + k0, &As[buf][(size_t)(tid + 256) * 8]);
        GLOAD_LDS16(gB + k0, &Bs[buf][(size_t)tid * 8]);
        if (BN == 128) GLOAD_LDS16(gB + (size_t)64 * ldb + k0, &Bs[buf][(size_t)(tid + 256) * 8]);
    };

    stage(0, 0);
    __syncthreads();
    int buf = 0;
    for (int k0 = 0; k0 < K; k0 += 32) {
        if (k0 + 32 < K) stage(buf ^ 1, k0 + 32);   // prefetch overlaps MFMA below
        const ushort_t* pa = &As[buf][(wm * (BM / 2) + r) * 32 + quad * 8];
        const ushort_t* pb = &Bs[buf][(wn * (BN / 2) + r) * 32 + quad * 8];
        short8 af[WTM], bf[WTN];
#pragma unroll
        for (int i = 0; i < WTM; ++i) af[i] = *(const short8*)(pa + i * 16 * 32);
#pragma unroll
        for (int j = 0; j < WTN; ++j) bf[j] = *(const short8*)(pb + j * 16 * 32);
#pragma unroll
        for (int i = 0; i < WTM; ++i)
#pragma unroll
            for (int j = 0; j < WTN; ++j)
                acc[i][j] = __builtin_amdgcn_mfma_f32_16x16x32_bf16(af[i], bf[j], acc[i][j], 0, 0, 0);
        __syncthreads();   // drains prefetch + protects buf for next overwrite
        buf ^= 1;
    }

    if (OUTMODE == 4) {
        // silu-pair epilogue: acc[i][even]=y1, acc[i][odd]=y3 of hp group
#pragma unroll
        for (int i = 0; i < WTM; ++i) {
            const int row = m0 + wm * (BM / 2) + i * 16 + quad * 4;
#pragma unroll
            for (int jp = 0; jp < WTN / 2; ++jp) {
                const int col = n0 / 2 + wn * (BN / 4) + jp * 16 + r;
#pragma unroll
                for (int t = 0; t < 4; ++t) {
                    const float a = acc[i][2 * jp][t];
                    const float b = acc[i][2 * jp + 1][t];
                    ((ushort_t*)C)[(size_t)(row + t) * ldc + col] =
                        f2bf(a / (1.f + __expf(-a)) * b);
                }
            }
        }
    } else {
#pragma unroll
        for (int i = 0; i < WTM; ++i) {
            const int row = m0 + wm * (BM / 2) + i * 16 + quad * 4;
#pragma unroll
            for (int j = 0; j < WTN; ++j) {
                const int col = n0 + wn * (BN / 2) + j * 16 + r;
#pragma unroll
                for (int t = 0; t < 4; ++t) {
                    const size_t off = (size_t)(row + t) * ldc + col;
                    const float v = acc[i][j][t];
                    if (OUTMODE == 2)      ((float*)C)[off] += v;
                    else if (OUTMODE == 1) ((ushort_t*)C)[off] = f2bf(v);
                    else                   ((float*)C)[off] = v;
                }
            }
        }
    }
}

// ---------------- Merged QK-projection (+fused RoPE) and V^T projection ----
// 288 blocks: lid 0..191 -> QK: C[s][n] = XN[s][:] . WQK[n][:], n in [0,1536),
//   epilogue rotates (2j,2j+1) pairs per head (RoPE) via lane-pair shuffle.
// lid 192..287 -> VT: C[d][s] = WVB[d][:] . XN[s][:]  (V^T, ldc=SEQL).
// Both: 128x128 tile, K=768, lda=ldb=768, bf16 out.
__global__ __launch_bounds__(256)
void gemm_qkvt_kernel(const ushort_t* __restrict__ XN_,
                      const ushort_t* __restrict__ WQK,
                      const ushort_t* __restrict__ WVB_,
                      ushort_t* __restrict__ QKB_,
                      ushort_t* __restrict__ VTG_)
{
    __shared__ __align__(16) ushort_t As[2][128 * 32];
    __shared__ __align__(16) ushort_t Bs[2][128 * 32];

    const int tid = threadIdx.x;
    const int lid0 = blockIdx.x;                 // 0..287
    const int lid  = (lid0 & 7) * 36 + (lid0 >> 3);   // bijective XCD swizzle (288/8=36)
    int job, bx, by;
    if (lid < 192) { job = 0; bx = lid & 15; by = lid >> 4; }       // 16 x 12
    else { const int t2 = lid - 192; job = 1; bx = t2 % 6; by = t2 / 6; }  // 6 x 16

    const ushort_t* A = job ? WVB_ : XN_;
    const ushort_t* B = job ? XN_  : WQK;

    const int wid = tid >> 6, lane = tid & 63;
    const int wm = wid & 1, wn = wid >> 1;
    const int r = lane & 15, quad = lane >> 4;
    const int m0 = bx * 128;
    const int n0 = by * 128;

    floatx4 acc[4][4];
#pragma unroll
    for (int i = 0; i < 4; ++i)
#pragma unroll
        for (int j = 0; j < 4; ++j) acc[i][j] = (floatx4){0.f, 0.f, 0.f, 0.f};

    const int row_a = tid >> 2;
    const int col8  = (tid & 3) * 8;
    const ushort_t* gA = A + (size_t)(m0 + row_a) * DIMC + col8;
    const ushort_t* gB = B + (size_t)(n0 + row_a) * DIMC + col8;

    auto stage = [&](int buf, int k0) {
        GLOAD_LDS16(gA + k0,                      &As[buf][(size_t)tid * 8]);
        GLOAD_LDS16(gA + (size_t)64 * DIMC + k0,  &As[buf][(size_t)(tid + 256) * 8]);
        GLOAD_LDS16(gB + k0,                      &Bs[buf][(size_t)tid * 8]);
        GLOAD_LDS16(gB + (size_t)64 * DIMC + k0,  &Bs[buf][(size_t)(tid + 256) * 8]);
    };

    stage(0, 0);
    __syncthreads();
    int buf = 0;
    for (int k0 = 0; k0 < DIMC; k0 += 32) {
        if (k0 + 32 < DIMC) stage(buf ^ 1, k0 + 32);
        const ushort_t* pa = &As[buf][(wm * 64 + r) * 32 + quad * 8];
        const ushort_t* pb = &Bs[buf][(wn * 64 + r) * 32 + quad * 8];
        short8 af[4], bf[4];
#pragma unroll
        for (int i = 0; i < 4; ++i) af[i] = *(const short8*)(pa + i * 16 * 32);
#pragma unroll
        for (int j = 0; j < 4; ++j) bf[j] = *(const short8*)(pb + j * 16 * 32);
#pragma unroll
        for (int i = 0; i < 4; ++i)
#pragma unroll
            for (int j = 0; j < 4; ++j)
                acc[i][j] = __builtin_amdgcn_mfma_f32_16x16x32_bf16(af[i], bf[j], acc[i][j], 0, 0, 0);
        __syncthreads();
        buf ^= 1;
    }

    if (job == 1) {   // V^T store
#pragma unroll
        for (int i = 0; i < 4; ++i) {
            const int row = m0 + wm * 64 + i * 16 + quad * 4;
#pragma unroll
            for (int j = 0; j < 4; ++j) {
                const int col = n0 + wn * 64 + j * 16 + r;
#pragma unroll
                for (int t = 0; t < 4; ++t)
                    VTG_[(size_t)(row + t) * SEQL + col] = f2bf(acc[i][j][t]);
            }
        }
    } else {          // QK store with fused RoPE (pairs are lane-neighbors)
#pragma unroll
        for (int j = 0; j < 4; ++j) {
            const int dh = j * 16 + r;            // d within head (<= 63)
            const float freq = __expf(-0.28782313662425574f * (float)(dh >> 1));
            const int col = n0 + wn * 64 + dh;
#pragma unroll
            for (int i = 0; i < 4; ++i) {
                const int row = m0 + wm * 64 + i * 16 + quad * 4;
#pragma unroll
                for (int t = 0; t < 4; ++t) {
                    const float ang = (float)(row + t) * freq;
                    const float cs = cosf(ang), sn = sinf(ang);
                    const float v  = acc[i][j][t];
                    const float pv = __shfl_xor(v, 1, 64);   // partner of the (2j,2j+1) pair
                    const float ov = (r & 1) ? (pv * sn + v * cs) : (v * cs - pv * sn);
                    QKB_[(size_t)(row + t) * QKS + col] = f2bf(ov);
                }
            }
        }
    }
}

// ---------------- RMSNorm: fp32 in -> bf16 out, one wave per row -----------
__global__ __launch_bounds__(256)
void rmsnorm_kernel(const float* __restrict__ x, const float* __restrict__ g,
                    ushort_t* __restrict__ out)
{
    const int w = threadIdx.x >> 6, lane = threadIdx.x & 63;
    const int row = blockIdx.x * 4 + w;
    const float* xr = x + (size_t)row * DIMC;
    float4 a = *(const float4*)(xr + lane * 4);
    float4 b = *(const float4*)(xr + 256 + lane * 4);
    float4 c = *(const float4*)(xr + 512 + lane * 4);
    float ss = a.x*a.x + a.y*a.y + a.z*a.z + a.w*a.w
             + b.x*b.x + b.y*b.y + b.z*b.z + b.w*b.w
             + c.x*c.x + c.y*c.y + c.z*c.z + c.w*c.w;
#pragma unroll
    for (int off = 32; off > 0; off >>= 1) ss += __shfl_xor(ss, off, 64);
    const float inv = rsqrtf(ss * (1.0f / DIMC) + 1e-6f);
    float4 ga = *(const float4*)(g + lane * 4);
    float4 gb = *(const float4*)(g + 256 + lane * 4);
    float4 gc = *(const float4*)(g + 512 + lane * 4);
    ushort_t* orow = out + (size_t)row * DIMC;
    *(ushort4*)(orow + lane * 4)       = make_ushort4(f2bf(a.x*inv*ga.x), f2bf(a.y*inv*ga.y), f2bf(a.z*inv*ga.z), f2bf(a.w*inv*ga.w));
    *(ushort4*)(orow + 256 + lane * 4) = make_ushort4(f2bf(b.x*inv*gb.x), f2bf(b.y*inv*gb.y), f2bf(b.z*inv*gb.z), f2bf(b.w*inv*gb.w));
    *(ushort4*)(orow + 512 + lane * 4) = make_ushort4(f2bf(c.x*inv*gc.x), f2bf(c.y*inv*gc.y), f2bf(c.z*inv*gc.z), f2bf(c.w*inv*gc.w));
}

// ---------------- MFMA flash attention, LDS-staged K/V, KVBLK=128 ----------
__global__ __launch_bounds__(256)
void attn_mfma_kernel(const ushort_t* __restrict__ Q, const ushort_t* __restrict__ K,
                      const ushort_t* __restrict__ VT, ushort_t* __restrict__ O,
                      int qks)
{
    __shared__ __align__(16) ushort_t Ks[2][128 * 64];   // [key][d], swizzled rows (128B)
    __shared__ __align__(16) ushort_t Vs[2][64 * 128];   // [d][key], swizzled rows (256B)

    const int tid = threadIdx.x;
    const int w = tid >> 6, lane = tid & 63;
    const int r = lane & 15, quad = lane >> 4;
    const int hb = blockIdx.y * HDIM;
    const int bx = 31 - (int)blockIdx.x;      // longest-first dispatch
    const int qb = bx * 64 + w * 16;          // wave q start
    const int nit = (bx + 2) >> 1;            // 128-key chunks

    const int krow = tid >> 3;
    const int kcol = ((tid & 7) ^ (krow & 7)) << 3;
    const int vrow = tid >> 4;
    const int vcol = (((tid & 15) ^ (vrow & 7))) << 3;
    const int swz = (r & 7) << 4;             // read-side byte XOR

    Frag bq[2];
    {
        const ushort_t* qp = Q + (size_t)(qb + r) * qks + hb + quad * 8;
#pragma unroll
        for (int fi = 0; fi < 2; ++fi) {
            Frag t; t.s8 = *(const short8*)(qp + fi * 32);
#pragma unroll
            for (int e = 0; e < 8; ++e) t.us[e] = f2bf(bf2f(t.us[e]) * 0.125f);
            bq[fi] = t;
        }
    }

    floatx4 o[4];
#pragma unroll
    for (int dg = 0; dg < 4; ++dg) o[dg] = (floatx4){0.f, 0.f, 0.f, 0.f};
    float m = -INFINITY, l = 0.f;

    auto stage = [&](int buf, int kc) {
        const ushort_t* kg = K + (size_t)(kc + krow) * qks + hb + kcol;
        GLOAD_LDS16(kg,                      &Ks[buf][(size_t)tid * 8]);
        GLOAD_LDS16(kg + (size_t)32 * qks,   &Ks[buf][(size_t)(tid + 256) * 8]);
        GLOAD_LDS16(kg + (size_t)64 * qks,   &Ks[buf][(size_t)(tid + 512) * 8]);
        GLOAD_LDS16(kg + (size_t)96 * qks,   &Ks[buf][(size_t)(tid + 768) * 8]);
        const ushort_t* vg = VT + (size_t)(hb + vrow) * SEQL + kc + vcol;
        GLOAD_LDS16(vg,                      &Vs[buf][(size_t)tid * 8]);
        GLOAD_LDS16(vg + (size_t)16 * SEQL,  &Vs[buf][(size_t)(tid + 256) * 8]);
        GLOAD_LDS16(vg + (size_t)32 * SEQL,  &Vs[buf][(size_t)(tid + 512) * 8]);
        GLOAD_LDS16(vg + (size_t)48 * SEQL,  &Vs[buf][(size_t)(tid + 768) * 8]);
    };

    stage(0, 0);
    __syncthreads();

    for (int it = 0; it < nit; ++it) {
        const int buf = it & 1;
        const int kc = it * 128;
        if (it + 1 < nit) stage(buf ^ 1, kc + 128);

        const char* ksb = (const char*)Ks[buf];
        const char* vsb = (const char*)Vs[buf];

        floatx4 st[8];
        __builtin_amdgcn_s_setprio(1);
#pragma unroll
        for (int s = 0; s < 8; ++s) {
            st[s] = (floatx4){0.f, 0.f, 0.f, 0.f};
#pragma unroll
            for (int f = 0; f < 2; ++f) {
                const int lb = (s * 16 + r) * 128 + ((f * 64 + quad * 16) ^ swz);
                const short8 a = *(const short8*)(ksb + lb);
                st[s] = __builtin_amdgcn_mfma_f32_16x16x32_bf16(a, bq[f].s8, st[s], 0, 0, 0);
            }
        }
        __builtin_amdgcn_s_setprio(0);

        if (it == nit - 1) {
            const int q = qb + r;
#pragma unroll
            for (int s = 0; s < 8; ++s)
#pragma unroll
                for (int tt = 0; tt < 4; ++tt)
                    if (kc + s * 16 + quad * 4 + tt > q) st[s][tt] = -INFINITY;
        }

        float vm = -INFINITY;
#pragma unroll
        for (int s = 0; s < 8; ++s)
            vm = fmaxf(vm, fmaxf(fmaxf(st[s][0], st[s][1]), fmaxf(st[s][2], st[s][3])));
        vm = fmaxf(vm, __shfl_xor(vm, 16, 64));
        vm = fmaxf(vm, __shfl_xor(vm, 32, 64));
        const float mnew = fmaxf(m, vm);
        const float alpha = __expf(m - mnew);
        float ps = 0.f;
#pragma unroll
        for (int s = 0; s < 8; ++s)
#pragma unroll
            for (int tt = 0; tt < 4; ++tt) {
                st[s][tt] = __expf(st[s][tt] - mnew);   // P in-place
                ps += st[s][tt];
            }
        ps += __shfl_xor(ps, 16, 64);
        ps += __shfl_xor(ps, 32, 64);
        l = l * alpha + ps;
        m = mnew;

        Frag ap[4];
#pragma unroll
        for (int ks = 0; ks < 4; ++ks) {
            ap[ks].u[0] = (uint32)f2bf(st[2*ks][0])   | ((uint32)f2bf(st[2*ks][1])   << 16);
            ap[ks].u[1] = (uint32)f2bf(st[2*ks][2])   | ((uint32)f2bf(st[2*ks][3])   << 16);
            ap[ks].u[2] = (uint32)f2bf(st[2*ks+1][0]) | ((uint32)f2bf(st[2*ks+1][1]) << 16);
            ap[ks].u[3] = (uint32)f2bf(st[2*ks+1][2]) | ((uint32)f2bf(st[2*ks+1][3]) << 16);
        }

        __builtin_amdgcn_s_setprio(1);
#pragma unroll
        for (int dg = 0; dg < 4; ++dg) {
            const int rowb = (dg * 16 + r) * 256;
            o[dg] *= alpha;
#pragma unroll
            for (int ks = 0; ks < 4; ++ks) {
                Frag av;
                *(uint2*)&av.u[0] = *(const uint2*)(vsb + rowb + ((ks * 64 + quad * 8) ^ swz));
                *(uint2*)&av.u[2] = *(const uint2*)(vsb + rowb + ((ks * 64 + 32 + quad * 8) ^ swz));
                o[dg] = __builtin_amdgcn_mfma_f32_16x16x32_bf16(av.s8, ap[ks].s8, o[dg], 0, 0, 0);
            }
        }
        __builtin_amdgcn_s_setprio(0);

        __syncthreads();
    }

    const float inv = 1.0f / l;
    ushort_t* op = O + (size_t)(qb + r) * DIMC + hb + quad * 4;
#pragma unroll
    for (int dg = 0; dg < 4; ++dg) {
        uint2 pkd;
        pkd.x = (uint32)f2bf(o[dg][0] * inv) | ((uint32)f2bf(o[dg][1] * inv) << 16);
        pkd.y = (uint32)f2bf(o[dg][2] * inv) | ((uint32)f2bf(o[dg][3] * inv) << 16);
        *(uint2*)(op + dg * 16) = pkd;
    }
}

// ---------------- Embedding gather (fp32) ----------------------------------
__global__ __launch_bounds__(256)
void embed_kernel(const int* __restrict__ tok, const float* __restrict__ emb,
                  float* __restrict__ h)
{
    const int idx = blockIdx.x * 256 + threadIdx.x;    // SEQL*192
    const int s = idx / 192, c = (idx % 192) * 4;
    const int t = tok[s];
    *(float4*)(h + (size_t)s * DIMC + c) = *(const float4*)(emb + (size_t)t * DIMC + c);
}

// ---------------- ALL-layer weight conversion fp32 -> bf16 -----------------
// WALL layout per layer l (stride LSTR elements):
//   [0, 2*QSZ)          : WQK  (wq rows 0..767, wk rows 768..1535)
//   [2*QSZ, 3*QSZ)      : WVB
//   [3*QSZ, 4*QSZ)      : WOB
//   [4*QSZ, 4*QSZ+2*PSZ): W13 interleaved: row = (hp>>4)*32 + src*16 + (hp&15)
//                         (src 0 = w1, 1 = w3; hp >= HIDV rows zero)
//   [.., +PSZ)          : W2P [768][2048], cols >= HIDV zero
// grid: dim3(LSTR/256, 4)
__global__ __launch_bounds__(256)
void conv_all_kernel(const float* __restrict__ wq, const float* __restrict__ wk,
                     const float* __restrict__ wv, const float* __restrict__ wo,
                     const float* __restrict__ w1, const float* __restrict__ w2,
                     const float* __restrict__ w3, ushort_t* __restrict__ wall)
{
    const int l = blockIdx.y;
    const int j = blockIdx.x * 256 + threadIdx.x;
    float v;
    if (j < 2 * QSZ) {
        v = (j < QSZ) ? wq[(size_t)l * QSZ + j] : wk[(size_t)l * QSZ + j - QSZ];
    } else if (j < 3 * QSZ) {
        v = wv[(size_t)l * QSZ + j - 2 * QSZ];
    } else if (j < 4 * QSZ) {
        v = wo[(size_t)l * QSZ + j - 3 * QSZ];
    } else if (j < 4 * QSZ + 2 * PSZ) {
        const int jj = j - 4 * QSZ;
        const int row = jj / DIMC, kk = jj - row * DIMC;
        const int hp = (row >> 5) * 16 + (row & 15);
        const int src = (row >> 4) & 1;
        v = (hp < HIDV) ? (src ? w3 : w1)[(size_t)l * W2SRC + (size_t)hp * DIMC + kk] : 0.f;
    } else {
        const int jj = j - 4 * QSZ - 2 * PSZ;
        const int n = jj >> 11, kk = jj & 2047;
        v = (kk < HIDV) ? w2[(size_t)l * W2SRC + (size_t)n * HIDV + kk] : 0.f;
    }
    wall[(size_t)l * LSTR + j] = f2bf(v);
}

// ---------------- out_w conversion fp32 -> bf16 ----------------------------
__global__ __launch_bounds__(256)
void conv_outw_kernel(const float* __restrict__ src, ushort_t* __restrict__ dst)
{
    const size_t idx = (size_t)(blockIdx.x * 256 + threadIdx.x);
    float4 a = *(const float4*)(src + idx * 4);
    *(ushort4*)(dst + idx * 4) = make_ushort4(f2bf(a.x), f2bf(a.y), f2bf(a.z), f2bf(a.w));
}

extern "C" void kernel_launch(void* const* d_in, const int* in_sizes, int n_in,
                              void* d_out, int out_size, void* d_ws, size_t ws_size,
                              hipStream_t stream)
{
    const int*   tok  = (const int*)d_in[0];
    const float* emb  = (const float*)d_in[1];
    const float* wq   = (const float*)d_in[2];
    const float* wk   = (const float*)d_in[3];
    const float* wv   = (const float*)d_in[4];
    const float* wo   = (const float*)d_in[5];
    const float* w1   = (const float*)d_in[6];
    const float* w2   = (const float*)d_in[7];
    const float* w3   = (const float*)d_in[8];
    const float* anw  = (const float*)d_in[9];
    const float* fnw  = (const float*)d_in[10];
    const float* nw   = (const float*)d_in[11];
    const float* outw = (const float*)d_in[12];
    float* out = (float*)d_out;
    (void)in_sizes; (void)n_in; (void)out_size; (void)ws_size;

    char* p = (char*)d_ws;
    auto alloc = [&](size_t bytes) { char* r = p; p += (bytes + 255) & ~(size_t)255; return r; };
    float*    H    = (float*)   alloc((size_t)SEQL * DIMC * 4);
    ushort_t* XN   = (ushort_t*)alloc((size_t)SEQL * DIMC * 2);
    ushort_t* YN   = (ushort_t*)alloc((size_t)SEQL * DIMC * 2);
    ushort_t* WALL = (ushort_t*)alloc((size_t)4 * LSTR * 2);      // all converted weights
    ushort_t* QKB  = (ushort_t*)alloc((size_t)SEQL * QKS * 2);    // fused Q|K [2048][1536]
    ushort_t* VTG  = (ushort_t*)alloc((size_t)SEQL * DIMC * 2);   // V^T [DIMC][SEQL]
    ushort_t* AO   = (ushort_t*)alloc((size_t)SEQL * DIMC * 2);
    ushort_t* HS   = (ushort_t*)alloc((size_t)SEQL * HIDP * 2);
    ushort_t* OUTWB= (ushort_t*)alloc((size_t)NVOCAB * DIMC * 2);

    embed_kernel<<<1536, 256, 0, stream>>>(tok, emb, H);
    conv_all_kernel<<<dim3(LSTR / 256, 4), 256, 0, stream>>>(wq, wk, wv, wo, w1, w2, w3, WALL);

    for (int l = 0; l < 4; ++l) {
        ushort_t* WL  = WALL + (size_t)l * LSTR;
        ushort_t* WQK = WL;
        ushort_t* WVB = WL + 2 * QSZ;
        ushort_t* WOB = WL + 3 * QSZ;
        ushort_t* W13 = WL + 4 * QSZ;
        ushort_t* W2P = WL + 4 * QSZ + 2 * PSZ;

        rmsnorm_kernel<<<512, 256, 0, stream>>>(H, anw + (size_t)l * DIMC, XN);

        // merged QK-proj (+RoPE) and V^T-proj, 288 blocks
        gemm_qkvt_kernel<<<288, 256, 0, stream>>>(XN, WQK, WVB, QKB, VTG);

        attn_mfma_kernel<<<dim3(32, NHEAD), 256, 0, stream>>>(QKB, QKB + 768, VTG, AO, QKS);

        // o @ wo^T, accumulate into H (residual): M=2048 N=768
        gemm_lds_kernel<128,64,2><<<dim3(16,12), 256, 0, stream>>>(AO, DIMC, WOB, DIMC, H, DIMC, DIMC);

        rmsnorm_kernel<<<512, 256, 0, stream>>>(H, fnw + (size_t)l * DIMC, YN);

        // FFN up with fused SiLU-pair epilogue: M=2048 N=4096(W13) -> HS [2048][2048] bf16
        gemm_lds_kernel<128,128,4><<<dim3(16,32), 256, 0, stream>>>(YN, DIMC, W13, DIMC, HS, HIDP, DIMC);

        // FFN down: M=2048 N=768 K=2048(pad), accumulate into H
        gemm_lds_kernel<128,64,2><<<dim3(16,12), 256, 0, stream>>>(HS, HIDP, W2P, HIDP, H, DIMC, HIDP);
    }

    rmsnorm_kernel<<<512, 256, 0, stream>>>(H, nw, XN);
    conv_outw_kernel<<<24000, 256, 0, stream>>>(outw, OUTWB);
    // logits: M=2048 N=32000 K=768, f32 out
    gemm_lds_kernel<128,128,0><<<dim3(16,250), 256, 0, stream>>>(XN, DIMC, OUTWB, DIMC, out, NVOCAB, DIMC);
}